// Round 9
// baseline (191.754 us; speedup 1.0000x reference)
//
#include <hip/hip_runtime.h>
#include <math.h>

#define BB 64
#define NN 1024
#define HID 64
#define STATE 32
#define NTYPES 10

typedef _Float16 f16;
typedef f16 f16x8 __attribute__((ext_vector_type(8)));
typedef f16 f16x4 __attribute__((ext_vector_type(4)));
typedef float f32x4 __attribute__((ext_vector_type(4)));

#define MFMA16(a, b, c) __builtin_amdgcn_mfma_f32_16x16x32_f16(a, b, c, 0, 0, 0)

__device__ __forceinline__ float sigm(float x) { return 1.f / (1.f + expf(-x)); }

__device__ __forceinline__ unsigned packh2(f16 a, f16 b) {
    union { f16 h[2]; unsigned u; } p;
    p.h[0] = a; p.h[1] = b;
    return p.u;
}

// ---------------- misc: weight swizzle into MFMA B-frag layout + zero cnt/ctx
__global__ __launch_bounds__(256) void k_misc(
    const float* __restrict__ w2, const float* __restrict__ gw,
    const float* __restrict__ hw1, f16* __restrict__ out,
    int* __restrict__ cnt, float* __restrict__ ctx)
{
    int p = blockIdx.x * 256 + threadIdx.x;
    if (p < 18432) {
        const float* W; int K, pl;
        if (p < 12288) { int seg = p >> 12; pl = p & 4095; W = (seg == 0) ? w2 : gw + (seg - 1) * 4096; K = 64; }
        else { W = hw1; K = 96; pl = p - 12288; }
        int j = pl & 7, lane = (pl >> 3) & 63, nt = (pl >> 9) & 3, ch = pl >> 11;
        int k = ch * 32 + ((lane >> 4) << 3) + j;
        int o = nt * 16 + (lane & 15);
        out[p] = (f16)W[o * K + k];
        return;
    }
    int q = p - 18432;
    if (q < BB * NTYPES) { cnt[q] = 0; return; }
    q -= BB * NTYPES;
    if (q < BB * HID) ctx[q] = 0.f;
}

// ---------------- encoder (MFMA) + fused bucketing; outputs nrm (f16) + scale (f32)
__global__ __launch_bounds__(256) void k_encoder(
    const float* __restrict__ feat,
    const float* __restrict__ w1, const float* __restrict__ b1,
    const f16* __restrict__ w2f, const float* __restrict__ b2,
    const int* __restrict__ types, int* __restrict__ idx, int* __restrict__ cnt,
    f16* __restrict__ nrm, float* __restrict__ sclv)
{
    __shared__ f16 w2s[4096];
    __shared__ f16 tmp[4][16 * 72];
    __shared__ float fbuf[4][48];
    int tid = threadIdx.x, wave = tid >> 6, lane = tid & 63;
    int l15 = lane & 15, quad = lane >> 4;
    if (tid < 64) {
        int row = blockIdx.x * 64 + tid;
        int b = row >> 10;
        int t = types[row];
        int pos = atomicAdd(&cnt[b * NTYPES + t], 1);
        idx[(b * NTYPES + t) * NN + pos] = row & (NN - 1);
    }
    { const uint4* s = (const uint4*)w2f; uint4* d = (uint4*)w2s;
      for (int i = tid; i < 512; i += 256) d[i] = s[i]; }
    float w10 = w1[lane * 3], w11 = w1[lane * 3 + 1], w12 = w1[lane * 3 + 2], b1l = b1[lane];
    int tb = blockIdx.x * 64 + wave * 16;
    if (lane < 48) fbuf[wave][lane] = feat[tb * 3 + lane];
    __syncthreads();
    f16* tw = &tmp[wave][0];
#pragma unroll
    for (int r = 0; r < 16; ++r) {
        float x0 = fbuf[wave][r * 3], x1 = fbuf[wave][r * 3 + 1], x2 = fbuf[wave][r * 3 + 2];
        float hv = fmaxf(fmaf(w10, x0, fmaf(w11, x1, fmaf(w12, x2, b1l))), 0.f);
        tw[r * 72 + lane] = (f16)hv;
    }
    __builtin_amdgcn_sched_barrier(0);
    f16x8 a0 = *(const f16x8*)&tw[l15 * 72 + quad * 8];
    f16x8 a1 = *(const f16x8*)&tw[l15 * 72 + 32 + quad * 8];
    const f16x8* bf = (const f16x8*)w2s;
    f32x4 acc[4];
#pragma unroll
    for (int nt = 0; nt < 4; ++nt) {
        f32x4 c = {0.f, 0.f, 0.f, 0.f};
        c = MFMA16(a0, bf[(0 * 4 + nt) * 64 + lane], c);
        c = MFMA16(a1, bf[(1 * 4 + nt) * 64 + lane], c);
        acc[nt] = c;
    }
    float b2c[4];
#pragma unroll
    for (int nt = 0; nt < 4; ++nt) b2c[nt] = b2[nt * 16 + l15];
#pragma unroll
    for (int i = 0; i < 4; ++i) {
        float v[4]; float ss = 0.f;
#pragma unroll
        for (int nt = 0; nt < 4; ++nt) { v[nt] = acc[nt][i] + b2c[nt]; ss = fmaf(v[nt], v[nt], ss); }
        ss += __shfl_xor(ss, 1, 64); ss += __shfl_xor(ss, 2, 64);
        ss += __shfl_xor(ss, 4, 64); ss += __shfl_xor(ss, 8, 64);
        float nm = fmaxf(sqrtf(ss), 1e-12f);
        float rinv = 1.f / nm;
        int grow = tb + quad * 4 + i;
#pragma unroll
        for (int nt = 0; nt < 4; ++nt)
            nrm[(size_t)grow * 64 + nt * 16 + l15] = (f16)(v[nt] * rinv);
        if (l15 == 0) sclv[grow] = nm;
    }
}

// ---------------- build M_j = nrmT(type j) @ h(type j) via MFMA; 64-row K-chunks
// if scale != null, h row = scale[m] * nrm row (layer 0).
#define TSTR2 72
__global__ __launch_bounds__(256) void k_buildM(
    const int* __restrict__ idx, const int* __restrict__ cnt,
    const f16* __restrict__ nrm, const f16* __restrict__ h,
    const float* __restrict__ scale, f16* __restrict__ M)
{
    __shared__ f16 nT[64 * TSTR2];
    __shared__ f16 hT[64 * TSTR2];
    int bj = blockIdx.x;
    int b = bj / NTYPES;
    int c = cnt[bj];
    const int* lst = idx + (size_t)bj * NN;
    int tid = threadIdx.x, wave = tid >> 6, lane = tid & 63;
    int l15 = lane & 15, quad = lane >> 4;
    int r = tid & 15;      // rows 4r..4r+3 of chunk
    int q4 = tid >> 4;     // cols 4q4..4q4+3
    const f16* nb = nrm + (size_t)b * NN * 64;
    const f16* hb = h + (size_t)b * NN * 64;
    const float* sb = scale ? scale + (size_t)b * NN : nullptr;
    f32x4 acc[4] = {{0.f,0.f,0.f,0.f},{0.f,0.f,0.f,0.f},{0.f,0.f,0.f,0.f},{0.f,0.f,0.f,0.f}};
    for (int k0 = 0; k0 < c; k0 += 64) {
        __syncthreads();
        f16x4 a[4], g[4];
#pragma unroll
        for (int u = 0; u < 4; ++u) { a[u] = (f16x4){0,0,0,0}; g[u] = (f16x4){0,0,0,0}; }
#pragma unroll
        for (int u = 0; u < 4; ++u) {
            int mi = k0 + 4 * r + u;
            if (mi < c) {
                int m = lst[mi];
                a[u] = *(const f16x4*)&nb[(size_t)m * 64 + 4 * q4];
                if (sb) { f16 sm = (f16)sb[m]; f16x4 sv = {sm, sm, sm, sm}; g[u] = a[u] * sv; }
                else g[u] = *(const f16x4*)&hb[(size_t)m * 64 + 4 * q4];
            }
        }
#pragma unroll
        for (int i = 0; i < 4; ++i) {
            *(unsigned*)&nT[(4 * q4 + i) * TSTR2 + 4 * r]     = packh2(a[0][i], a[1][i]);
            *(unsigned*)&nT[(4 * q4 + i) * TSTR2 + 4 * r + 2] = packh2(a[2][i], a[3][i]);
            *(unsigned*)&hT[(4 * q4 + i) * TSTR2 + 4 * r]     = packh2(g[0][i], g[1][i]);
            *(unsigned*)&hT[(4 * q4 + i) * TSTR2 + 4 * r + 2] = packh2(g[2][i], g[3][i]);
        }
        __syncthreads();
        f16x8 af0 = *(const f16x8*)&nT[(wave * 16 + l15) * TSTR2 + quad * 8];
        f16x8 af1 = *(const f16x8*)&nT[(wave * 16 + l15) * TSTR2 + 32 + quad * 8];
#pragma unroll
        for (int nt = 0; nt < 4; ++nt) {
            f16x8 bf0 = *(const f16x8*)&hT[(nt * 16 + l15) * TSTR2 + quad * 8];
            f16x8 bf1 = *(const f16x8*)&hT[(nt * 16 + l15) * TSTR2 + 32 + quad * 8];
            acc[nt] = MFMA16(af0, bf0, acc[nt]);
            acc[nt] = MFMA16(af1, bf1, acc[nt]);
        }
    }
    f16* Mo = M + (size_t)bj * 4096;
#pragma unroll
    for (int nt = 0; nt < 4; ++nt)
#pragma unroll
        for (int i = 0; i < 4; ++i)
            Mo[(wave * 16 + quad * 4 + i) * 64 + nt * 16 + l15] = (f16)acc[nt][i];
}

// ---------------- GNN layer (2x row-sliced, fused C&D build):
//   C = sum_j sig(cont[t,j]) M_j, D = C@gw^T -> LDS B-frag
//   layer0 (scale!=null): h1 = relu(nrm@D + s_row*(nrm@gw^T) + gb) -> hout
//   layer1 (hw1f!=null):  Z = relu(nrm@D + h@gw^T + gb); ctx += colsum(Z);
//                         P = Z @ hw1a^T -> hout (h2 never materialized)
__global__ __launch_bounds__(256) void k_gnn_layer(
    const int* __restrict__ idx, const int* __restrict__ cnt,
    const float* __restrict__ cont, const f16* __restrict__ M,
    const f16* __restrict__ nrm, const f16* __restrict__ h,
    const float* __restrict__ scale,
    const f16* __restrict__ gwf, const float* __restrict__ gb,
    const f16* __restrict__ hw1f,
    f16* __restrict__ hout, float* __restrict__ ctx)
{
    __shared__ f16 ds_[4096];
    __shared__ f16 gs[4096];
    __shared__ f16 tmp[4][16 * 72];
    int blk = blockIdx.x;
    int s = blk & 1, bt = blk >> 1;
    int b = bt / NTYPES, t = bt % NTYPES;
    int c = cnt[bt];
    if (c == 0) return;
    int tid = threadIdx.x, wave = tid >> 6, lane = tid & 63;
    int l15 = lane & 15, quad = lane >> 4;
    { const uint4* s2 = (const uint4*)gwf; uint4* d2 = (uint4*)gs;
      for (int i = tid; i < 512; i += 256) d2[i] = s2[i]; }
    // C strip (rows 16*wave .. +15) into f32 regs, from f16 M
    float sg[NTYPES];
#pragma unroll
    for (int j = 0; j < NTYPES; ++j) sg[j] = sigm(cont[t * NTYPES + j]);
    float ca[16];
#pragma unroll
    for (int i = 0; i < 16; ++i) ca[i] = 0.f;
    const f16* Mb = M + (size_t)b * NTYPES * 4096;
#pragma unroll
    for (int j = 0; j < NTYPES; ++j) {
        const f16* Mr = Mb + j * 4096 + (wave * 16 + l15) * 64;
        f16x8 m0 = *(const f16x8*)&Mr[quad * 8];
        f16x8 m1 = *(const f16x8*)&Mr[32 + quad * 8];
        float sv = sg[j];
#pragma unroll
        for (int e = 0; e < 8; ++e) {
            ca[e]     = fmaf(sv, (float)m0[e], ca[e]);
            ca[8 + e] = fmaf(sv, (float)m1[e], ca[8 + e]);
        }
    }
    f16x8 ca0, ca1;
#pragma unroll
    for (int i = 0; i < 8; ++i) { ca0[i] = (f16)ca[i]; ca1[i] = (f16)ca[8 + i]; }
    __syncthreads();   // gs ready
    const f16x8* gbf = (const f16x8*)gs;
#pragma unroll
    for (int nt = 0; nt < 4; ++nt) {
        f32x4 dd = {0.f, 0.f, 0.f, 0.f};
        dd = MFMA16(ca0, gbf[(0 * 4 + nt) * 64 + lane], dd);
        dd = MFMA16(ca1, gbf[(1 * 4 + nt) * 64 + lane], dd);
#pragma unroll
        for (int i = 0; i < 4; ++i) {
            int d = wave * 16 + quad * 4 + i;
            int pos = (((d >> 5) * 4 + nt) * 64 + ((d >> 3) & 3) * 16 + l15) * 8 + (d & 7);
            ds_[pos] = (f16)dd[i];
        }
    }
    __syncthreads();   // D ready
    float gbl[4];
#pragma unroll
    for (int nt = 0; nt < 4; ++nt) gbl[nt] = gb[nt * 16 + l15];
    const int* lst = idx + (size_t)bt * NN;
    const f16* nb = nrm + (size_t)b * NN * 64;
    const f16* hb = h + (size_t)b * NN * 64;
    const float* sb = scale ? scale + (size_t)b * NN : nullptr;
    f16* hob = hout + (size_t)b * NN * 64;
    const f16x8* dbf = (const f16x8*)ds_;
    const f16x8* hwbf = (const f16x8*)hw1f;   // global B-frags for P (L2-hot)
    f16* tw = &tmp[wave][0];
    float cacc[4] = {0.f, 0.f, 0.f, 0.f};
    for (int g = (s << 2) | wave; g * 16 < c; g += 8) {
        int tb = g * 16;
        int rA = tb + l15; if (rA >= c) rA = c - 1;
        int mA = lst[rA];
        const f16* na = nb + (size_t)mA * 64;
        f16x8 a0 = *(const f16x8*)&na[quad * 8];
        f16x8 a1 = *(const f16x8*)&na[32 + quad * 8];
        if (sb) {
            // layer 0
            f32x4 acc1[4], acc2[4];
#pragma unroll
            for (int nt = 0; nt < 4; ++nt) {
                f32x4 c1 = {0.f, 0.f, 0.f, 0.f}, c2 = {0.f, 0.f, 0.f, 0.f};
                c1 = MFMA16(a0, dbf[(0 * 4 + nt) * 64 + lane], c1);
                c1 = MFMA16(a1, dbf[(1 * 4 + nt) * 64 + lane], c1);
                c2 = MFMA16(a0, gbf[(0 * 4 + nt) * 64 + lane], c2);
                c2 = MFMA16(a1, gbf[(1 * 4 + nt) * 64 + lane], c2);
                acc1[nt] = c1; acc2[nt] = c2;
            }
#pragma unroll
            for (int i = 0; i < 4; ++i) {
                int rr = tb + quad * 4 + i;
                if (rr < c) {
                    int m = lst[rr];
                    float sm = sb[m];
#pragma unroll
                    for (int nt = 0; nt < 4; ++nt) {
                        float v = fmaxf(fmaf(sm, acc2[nt][i], acc1[nt][i]) + gbl[nt], 0.f);
                        hob[(size_t)m * 64 + nt * 16 + l15] = (f16)v;
                    }
                }
            }
        } else {
            // layer 1: Z = relu(nrm@D + h@G + gb); ctx; P = Z@hw1a^T
            const f16* ha = hb + (size_t)mA * 64;
            f16x8 h0 = *(const f16x8*)&ha[quad * 8];
            f16x8 h1 = *(const f16x8*)&ha[32 + quad * 8];
            f32x4 acc[4];
#pragma unroll
            for (int nt = 0; nt < 4; ++nt) {
                f32x4 cc = {0.f, 0.f, 0.f, 0.f};
                cc = MFMA16(a0, dbf[(0 * 4 + nt) * 64 + lane], cc);
                cc = MFMA16(a1, dbf[(1 * 4 + nt) * 64 + lane], cc);
                cc = MFMA16(h0, gbf[(0 * 4 + nt) * 64 + lane], cc);
                cc = MFMA16(h1, gbf[(1 * 4 + nt) * 64 + lane], cc);
                acc[nt] = cc;
            }
            int mS[4]; bool ok[4];
#pragma unroll
            for (int i = 0; i < 4; ++i) {
                int rr = tb + quad * 4 + i;
                ok[i] = rr < c;
                mS[i] = lst[ok[i] ? rr : c - 1];
#pragma unroll
                for (int nt = 0; nt < 4; ++nt) {
                    float v = fmaxf(acc[nt][i] + gbl[nt], 0.f);
                    if (ok[i]) cacc[nt] += v;
                    tw[(quad * 4 + i) * 72 + nt * 16 + l15] = (f16)v;
                }
            }
            __builtin_amdgcn_sched_barrier(0);
            f16x8 t0 = *(const f16x8*)&tw[l15 * 72 + quad * 8];
            f16x8 t1 = *(const f16x8*)&tw[l15 * 72 + 32 + quad * 8];
#pragma unroll
            for (int nt = 0; nt < 4; ++nt) {
                f32x4 pp = {0.f, 0.f, 0.f, 0.f};
                pp = MFMA16(t0, hwbf[(0 * 4 + nt) * 64 + lane], pp);
                pp = MFMA16(t1, hwbf[(1 * 4 + nt) * 64 + lane], pp);
#pragma unroll
                for (int i = 0; i < 4; ++i)
                    if (ok[i]) hob[(size_t)mS[i] * 64 + nt * 16 + l15] = (f16)pp[i];
            }
            __builtin_amdgcn_sched_barrier(0);
        }
    }
    if (ctx) {
#pragma unroll
        for (int nt = 0; nt < 4; ++nt) {
            float sv = cacc[nt];
            sv += __shfl_xor(sv, 16, 64);
            sv += __shfl_xor(sv, 32, 64);
            if (quad == 0) atomicAdd(&ctx[b * HID + nt * 16 + l15], sv);
        }
    }
}

// ---------------- head (no MFMA): GRU + stpart = st@W1b^T + b1;
//                  lat[row] = relu(P[row] + stpart) . w2 + b2
__global__ __launch_bounds__(256) void k_head(
    const f16* __restrict__ P, const float* __restrict__ ctx_sum,
    const float* __restrict__ prev,
    const float* __restrict__ w_ih, const float* __restrict__ w_hh,
    const float* __restrict__ b_ih, const float* __restrict__ b_hh,
    const float* __restrict__ hw1, const float* __restrict__ b1,
    const float* __restrict__ w2, const float* __restrict__ b2,
    float* __restrict__ lat, float* __restrict__ state_out)
{
    __shared__ float st[STATE], cs[HID], ps[STATE], gis[96], ghs[96];
    __shared__ float stp[HID], w2s[HID];
    int tid = threadIdx.x;
    int b = blockIdx.x >> 4;
    if (tid < HID) cs[tid] = ctx_sum[b * HID + tid] * (1.f / NN);
    if (tid >= HID && tid < HID + STATE) ps[tid - HID] = prev[b * STATE + tid - HID];
    if (tid >= 96 && tid < 96 + HID) w2s[tid - 96] = w2[tid - 96];
    __syncthreads();
    if (tid < 96) {
        float gi = b_ih[tid];
#pragma unroll 8
        for (int k = 0; k < HID; ++k) gi = fmaf(w_ih[tid * HID + k], cs[k], gi);
        float gh = b_hh[tid];
#pragma unroll
        for (int k = 0; k < STATE; ++k) gh = fmaf(w_hh[tid * STATE + k], ps[k], gh);
        gis[tid] = gi; ghs[tid] = gh;
    }
    __syncthreads();
    if (tid < STATE) {
        float r = sigm(gis[tid] + ghs[tid]);
        float z = sigm(gis[32 + tid] + ghs[32 + tid]);
        float nn = tanhf(gis[64 + tid] + r * ghs[64 + tid]);
        float v = (1.f - z) * nn + z * ps[tid];
        st[tid] = v;
        if ((blockIdx.x & 15) == 0) state_out[b * STATE + tid] = v;
    }
    __syncthreads();
    if (tid < HID) {
        float a = b1[tid];
#pragma unroll
        for (int k = 0; k < STATE; ++k) a = fmaf(hw1[tid * 96 + 64 + k], st[k], a);
        stp[tid] = a;
    }
    __syncthreads();
    int wave = tid >> 6, lane = tid & 63;
    float b2v = b2[0];
    int row = blockIdx.x * 64 + wave * 16 + (lane >> 2);
    int cc = (lane & 3) * 16;
    const f16* pr = P + (size_t)row * 64 + cc;
    f16x8 p0 = *(const f16x8*)pr;
    f16x8 p1 = *(const f16x8*)(pr + 8);
    float sum = 0.f;
#pragma unroll
    for (int e = 0; e < 8; ++e) {
        float u0 = (float)p0[e] + stp[cc + e];
        sum = fmaf(fmaxf(u0, 0.f), w2s[cc + e], sum);
        float u1 = (float)p1[e] + stp[cc + 8 + e];
        sum = fmaf(fmaxf(u1, 0.f), w2s[cc + 8 + e], sum);
    }
    sum += __shfl_xor(sum, 1, 64);
    sum += __shfl_xor(sum, 2, 64);
    if ((lane & 3) == 0) lat[row] = sum + b2v;
}

extern "C" void kernel_launch(void* const* d_in, const int* in_sizes, int n_in,
                              void* d_out, int out_size, void* d_ws, size_t ws_size,
                              hipStream_t stream) {
    const float* feat   = (const float*)d_in[0];
    const int*   types  = (const int*)d_in[1];
    const float* prev   = (const float*)d_in[2];
    const float* enc_w1 = (const float*)d_in[3];
    const float* enc_b1 = (const float*)d_in[4];
    const float* enc_w2 = (const float*)d_in[5];
    const float* enc_b2 = (const float*)d_in[6];
    const float* cont   = (const float*)d_in[7];
    const float* gnn_w  = (const float*)d_in[8];
    const float* gnn_b  = (const float*)d_in[9];
    const float* w_ih   = (const float*)d_in[10];
    const float* w_hh   = (const float*)d_in[11];
    const float* b_ih   = (const float*)d_in[12];
    const float* b_hh   = (const float*)d_in[13];
    const float* hw1    = (const float*)d_in[14];
    const float* hb1    = (const float*)d_in[15];
    const float* hw2    = (const float*)d_in[16];
    const float* hb2    = (const float*)d_in[17];
    float* out = (float*)d_out;

    float* ws  = (float*)d_ws;
    f16*   nrm = (f16*)ws;                    // 4194304 f16
    f16*   h1  = (f16*)(ws + 2097152);        // 4194304 f16
    f16*   P   = (f16*)(ws + 4194304);        // 4194304 f16
    float* scl = ws + 6291456;                // 65536 f32
    int*   idx = (int*)(ws + 6356992);        // 655360 i32
    int*   cnt = idx + BB * NTYPES * NN;      // 640 i32
    f16*   M0  = (f16*)(ws + 7012992);        // 2621440 f16
    f16*   M1  = (f16*)(ws + 8323712);        // 2621440 f16
    f16*   wfrag = (f16*)(ws + 9634432);      // 18432 f16
    float* ctx   = ws + 9643648;              // 4096 f32
    f16*   w2f  = wfrag;
    f16*   gw0f = wfrag + 4096;
    f16*   gw1f = wfrag + 8192;
    f16*   hwf  = wfrag + 12288;

    k_misc<<<91, 256, 0, stream>>>(enc_w2, gnn_w, hw1, wfrag, cnt, ctx);
    k_encoder<<<BB * NN / 64, 256, 0, stream>>>(feat, enc_w1, enc_b1, w2f, enc_b2,
                                                types, idx, cnt, nrm, scl);
    // layer 0: h0 = scl*nrm -> h1
    k_buildM<<<BB * NTYPES, 256, 0, stream>>>(idx, cnt, nrm, nrm, scl, M0);
    k_gnn_layer<<<BB * NTYPES * 2, 256, 0, stream>>>(idx, cnt, cont, M0, nrm, nrm, scl,
                                                     gw0f, gnn_b, nullptr, h1, nullptr);
    // layer 1: h1 -> Z (regs only) -> ctx + P = Z@hw1a^T
    k_buildM<<<BB * NTYPES, 256, 0, stream>>>(idx, cnt, nrm, h1, nullptr, M1);
    k_gnn_layer<<<BB * NTYPES * 2, 256, 0, stream>>>(idx, cnt, cont, M1, nrm, h1, nullptr,
                                                     gw1f, gnn_b + HID, hwf, P, ctx);
    // head (+ fused GRU); new_state written to out tail
    k_head<<<BB * NN / 64, 256, 0, stream>>>(P, ctx, prev, w_ih, w_hh, b_ih, b_hh,
                                             hw1, hb1, hw2, hb2, out, out + BB * NN);
}

// Round 10
// 177.317 us; speedup vs baseline: 1.0814x; 1.0814x over previous
//
#include <hip/hip_runtime.h>
#include <math.h>

#define BB 64
#define NN 1024
#define HID 64
#define STATE 32
#define NTYPES 10

typedef _Float16 f16;
typedef f16 f16x8 __attribute__((ext_vector_type(8)));
typedef f16 f16x4 __attribute__((ext_vector_type(4)));
typedef float f32x4 __attribute__((ext_vector_type(4)));

#define MFMA16(a, b, c) __builtin_amdgcn_mfma_f32_16x16x32_f16(a, b, c, 0, 0, 0)

__device__ __forceinline__ float sigm(float x) { return 1.f / (1.f + expf(-x)); }

__device__ __forceinline__ f16x8 cvt8(float4 a, float4 b) {
    f16x8 r;
    r[0] = (f16)a.x; r[1] = (f16)a.y; r[2] = (f16)a.z; r[3] = (f16)a.w;
    r[4] = (f16)b.x; r[5] = (f16)b.y; r[6] = (f16)b.z; r[7] = (f16)b.w;
    return r;
}
__device__ __forceinline__ unsigned packh2(f16 a, f16 b) {
    union { f16 h[2]; unsigned u; } p;
    p.h[0] = a; p.h[1] = b;
    return p.u;
}

// ---------------- misc: weight swizzle into MFMA B-frag layout + zero cnt/ctx
__global__ __launch_bounds__(256) void k_misc(
    const float* __restrict__ w2, const float* __restrict__ gw,
    const float* __restrict__ hw1, f16* __restrict__ out,
    int* __restrict__ cnt, float* __restrict__ ctx)
{
    int p = blockIdx.x * 256 + threadIdx.x;
    if (p < 18432) {
        const float* W; int K, pl;
        if (p < 12288) { int seg = p >> 12; pl = p & 4095; W = (seg == 0) ? w2 : gw + (seg - 1) * 4096; K = 64; }
        else { W = hw1; K = 96; pl = p - 12288; }
        int j = pl & 7, lane = (pl >> 3) & 63, nt = (pl >> 9) & 3, ch = pl >> 11;
        int k = ch * 32 + ((lane >> 4) << 3) + j;
        int o = nt * 16 + (lane & 15);
        out[p] = (f16)W[o * K + k];
        return;
    }
    int q = p - 18432;
    if (q < BB * NTYPES) { cnt[q] = 0; return; }
    q -= BB * NTYPES;
    if (q < BB * HID) ctx[q] = 0.f;
}

// ---------------- encoder (MFMA) + fused bucketing; outputs nrm (f16) + scale (f32)
__global__ __launch_bounds__(256) void k_encoder(
    const float* __restrict__ feat,
    const float* __restrict__ w1, const float* __restrict__ b1,
    const f16* __restrict__ w2f, const float* __restrict__ b2,
    const int* __restrict__ types, int* __restrict__ idx, int* __restrict__ cnt,
    f16* __restrict__ nrm, float* __restrict__ sclv)
{
    __shared__ f16 w2s[4096];
    __shared__ f16 tmp[4][16 * 72];
    __shared__ float fbuf[4][48];
    int tid = threadIdx.x, wave = tid >> 6, lane = tid & 63;
    int l15 = lane & 15, quad = lane >> 4;
    if (tid < 64) {
        int row = blockIdx.x * 64 + tid;
        int b = row >> 10;
        int t = types[row];
        int pos = atomicAdd(&cnt[b * NTYPES + t], 1);
        idx[(b * NTYPES + t) * NN + pos] = row & (NN - 1);
    }
    { const uint4* s = (const uint4*)w2f; uint4* d = (uint4*)w2s;
      for (int i = tid; i < 512; i += 256) d[i] = s[i]; }
    float w10 = w1[lane * 3], w11 = w1[lane * 3 + 1], w12 = w1[lane * 3 + 2], b1l = b1[lane];
    int tb = blockIdx.x * 64 + wave * 16;
    if (lane < 48) fbuf[wave][lane] = feat[tb * 3 + lane];
    __syncthreads();
    f16* tw = &tmp[wave][0];
#pragma unroll
    for (int r = 0; r < 16; ++r) {
        float x0 = fbuf[wave][r * 3], x1 = fbuf[wave][r * 3 + 1], x2 = fbuf[wave][r * 3 + 2];
        float hv = fmaxf(fmaf(w10, x0, fmaf(w11, x1, fmaf(w12, x2, b1l))), 0.f);
        tw[r * 72 + lane] = (f16)hv;
    }
    __builtin_amdgcn_sched_barrier(0);
    f16x8 a0 = *(const f16x8*)&tw[l15 * 72 + quad * 8];
    f16x8 a1 = *(const f16x8*)&tw[l15 * 72 + 32 + quad * 8];
    const f16x8* bf = (const f16x8*)w2s;
    f32x4 acc[4];
#pragma unroll
    for (int nt = 0; nt < 4; ++nt) {
        f32x4 c = {0.f, 0.f, 0.f, 0.f};
        c = MFMA16(a0, bf[(0 * 4 + nt) * 64 + lane], c);
        c = MFMA16(a1, bf[(1 * 4 + nt) * 64 + lane], c);
        acc[nt] = c;
    }
    float b2c[4];
#pragma unroll
    for (int nt = 0; nt < 4; ++nt) b2c[nt] = b2[nt * 16 + l15];
#pragma unroll
    for (int i = 0; i < 4; ++i) {
        float v[4]; float ss = 0.f;
#pragma unroll
        for (int nt = 0; nt < 4; ++nt) { v[nt] = acc[nt][i] + b2c[nt]; ss = fmaf(v[nt], v[nt], ss); }
        ss += __shfl_xor(ss, 1, 64); ss += __shfl_xor(ss, 2, 64);
        ss += __shfl_xor(ss, 4, 64); ss += __shfl_xor(ss, 8, 64);
        float nm = fmaxf(sqrtf(ss), 1e-12f);
        float rinv = 1.f / nm;
        int grow = tb + quad * 4 + i;
#pragma unroll
        for (int nt = 0; nt < 4; ++nt)
            nrm[(size_t)grow * 64 + nt * 16 + l15] = (f16)(v[nt] * rinv);
        if (l15 == 0) sclv[grow] = nm;
    }
}

// ---------------- build M_j = nrmT(type j) @ h(type j) via MFMA; 64-row K-chunks
// if scale != null, h row = scale[m] * nrm row (layer 0).
#define TSTR2 72
__global__ __launch_bounds__(256) void k_buildM(
    const int* __restrict__ idx, const int* __restrict__ cnt,
    const f16* __restrict__ nrm, const f16* __restrict__ h,
    const float* __restrict__ scale, f16* __restrict__ M)
{
    __shared__ f16 nT[64 * TSTR2];
    __shared__ f16 hT[64 * TSTR2];
    int bj = blockIdx.x;
    int b = bj / NTYPES;
    int c = cnt[bj];
    const int* lst = idx + (size_t)bj * NN;
    int tid = threadIdx.x, wave = tid >> 6, lane = tid & 63;
    int l15 = lane & 15, quad = lane >> 4;
    int r = tid & 15;      // rows 4r..4r+3 of chunk
    int q4 = tid >> 4;     // cols 4q4..4q4+3
    const f16* nb = nrm + (size_t)b * NN * 64;
    const f16* hb = h + (size_t)b * NN * 64;
    const float* sb = scale ? scale + (size_t)b * NN : nullptr;
    f32x4 acc[4] = {{0.f,0.f,0.f,0.f},{0.f,0.f,0.f,0.f},{0.f,0.f,0.f,0.f},{0.f,0.f,0.f,0.f}};
    for (int k0 = 0; k0 < c; k0 += 64) {
        __syncthreads();
        f16x4 a[4], g[4];
#pragma unroll
        for (int u = 0; u < 4; ++u) { a[u] = (f16x4){0,0,0,0}; g[u] = (f16x4){0,0,0,0}; }
#pragma unroll
        for (int u = 0; u < 4; ++u) {
            int mi = k0 + 4 * r + u;
            if (mi < c) {
                int m = lst[mi];
                a[u] = *(const f16x4*)&nb[(size_t)m * 64 + 4 * q4];
                if (sb) { f16 sm = (f16)sb[m]; f16x4 sv = {sm, sm, sm, sm}; g[u] = a[u] * sv; }
                else g[u] = *(const f16x4*)&hb[(size_t)m * 64 + 4 * q4];
            }
        }
#pragma unroll
        for (int i = 0; i < 4; ++i) {
            *(unsigned*)&nT[(4 * q4 + i) * TSTR2 + 4 * r]     = packh2(a[0][i], a[1][i]);
            *(unsigned*)&nT[(4 * q4 + i) * TSTR2 + 4 * r + 2] = packh2(a[2][i], a[3][i]);
            *(unsigned*)&hT[(4 * q4 + i) * TSTR2 + 4 * r]     = packh2(g[0][i], g[1][i]);
            *(unsigned*)&hT[(4 * q4 + i) * TSTR2 + 4 * r + 2] = packh2(g[2][i], g[3][i]);
        }
        __syncthreads();
        f16x8 af0 = *(const f16x8*)&nT[(wave * 16 + l15) * TSTR2 + quad * 8];
        f16x8 af1 = *(const f16x8*)&nT[(wave * 16 + l15) * TSTR2 + 32 + quad * 8];
#pragma unroll
        for (int nt = 0; nt < 4; ++nt) {
            f16x8 bf0 = *(const f16x8*)&hT[(nt * 16 + l15) * TSTR2 + quad * 8];
            f16x8 bf1 = *(const f16x8*)&hT[(nt * 16 + l15) * TSTR2 + 32 + quad * 8];
            acc[nt] = MFMA16(af0, bf0, acc[nt]);
            acc[nt] = MFMA16(af1, bf1, acc[nt]);
        }
    }
    f16* Mo = M + (size_t)bj * 4096;
#pragma unroll
    for (int nt = 0; nt < 4; ++nt)
#pragma unroll
        for (int i = 0; i < 4; ++i)
            Mo[(wave * 16 + quad * 4 + i) * 64 + nt * 16 + l15] = (f16)acc[nt][i];
}

// ---------------- GNN layer (un-sliced, fused C&D build, XCD-swizzled grid):
//   C = sum_j sig(cont[t,j]) M_j (A-frags in regs), D = C@gw^T -> LDS B-frag
//   layer0 (scale!=null): out = relu(nrm@D + s_row*(nrm@gw^T) + gb)
//   layer1:               out = relu(nrm@D + h@gw^T + gb), ctx += colsum
__global__ __launch_bounds__(256) void k_gnn_layer(
    const int* __restrict__ idx, const int* __restrict__ cnt,
    const float* __restrict__ cont, const f16* __restrict__ M,
    const f16* __restrict__ nrm, const f16* __restrict__ h,
    const float* __restrict__ scale,
    const f16* __restrict__ gwf, const float* __restrict__ gb,
    f16* __restrict__ hout, float* __restrict__ ctx)
{
    __shared__ f16 ds_[4096];
    __shared__ f16 gs[4096];
    // XCD swizzle: all 10 t-blocks of a batch b land on the same XCD so the
    // 80 KB M_b stream is fetched into that XCD's L2 once and reused 10x.
    int i0 = blockIdx.x;
    int xcd = i0 & 7, k = i0 >> 3;            // k in 0..79
    int b = xcd + 8 * (k / NTYPES);
    int t = k % NTYPES;
    int bt = b * NTYPES + t;
    int c = cnt[bt];
    if (c == 0) return;
    int tid = threadIdx.x, wave = tid >> 6, lane = tid & 63;
    int l15 = lane & 15, quad = lane >> 4;
    { const uint4* s2 = (const uint4*)gwf; uint4* d2 = (uint4*)gs;
      for (int i = tid; i < 512; i += 256) d2[i] = s2[i]; }
    // C strip (rows 16*wave .. +15) into f32 regs, from f16 M
    float sg[NTYPES];
#pragma unroll
    for (int j = 0; j < NTYPES; ++j) sg[j] = sigm(cont[t * NTYPES + j]);
    float ca[16];
#pragma unroll
    for (int i = 0; i < 16; ++i) ca[i] = 0.f;
    const f16* Mb = M + (size_t)b * NTYPES * 4096;
#pragma unroll
    for (int j = 0; j < NTYPES; ++j) {
        const f16* Mr = Mb + j * 4096 + (wave * 16 + l15) * 64;
        f16x8 m0 = *(const f16x8*)&Mr[quad * 8];
        f16x8 m1 = *(const f16x8*)&Mr[32 + quad * 8];
        float sv = sg[j];
#pragma unroll
        for (int e = 0; e < 8; ++e) {
            ca[e]     = fmaf(sv, (float)m0[e], ca[e]);
            ca[8 + e] = fmaf(sv, (float)m1[e], ca[8 + e]);
        }
    }
    f16x8 ca0, ca1;
#pragma unroll
    for (int i = 0; i < 8; ++i) { ca0[i] = (f16)ca[i]; ca1[i] = (f16)ca[8 + i]; }
    __syncthreads();   // gs ready
    const f16x8* gbf = (const f16x8*)gs;
#pragma unroll
    for (int nt = 0; nt < 4; ++nt) {
        f32x4 dd = {0.f, 0.f, 0.f, 0.f};
        dd = MFMA16(ca0, gbf[(0 * 4 + nt) * 64 + lane], dd);
        dd = MFMA16(ca1, gbf[(1 * 4 + nt) * 64 + lane], dd);
#pragma unroll
        for (int i = 0; i < 4; ++i) {
            int d = wave * 16 + quad * 4 + i;
            int pos = (((d >> 5) * 4 + nt) * 64 + ((d >> 3) & 3) * 16 + l15) * 8 + (d & 7);
            ds_[pos] = (f16)dd[i];
        }
    }
    __syncthreads();   // D ready
    float gbl[4];
#pragma unroll
    for (int nt = 0; nt < 4; ++nt) gbl[nt] = gb[nt * 16 + l15];
    const int* lst = idx + (size_t)bt * NN;
    const f16* nb = nrm + (size_t)b * NN * 64;
    const f16* hb = h + (size_t)b * NN * 64;
    const float* sb = scale ? scale + (size_t)b * NN : nullptr;
    f16* hob = hout + (size_t)b * NN * 64;
    const f16x8* dbf = (const f16x8*)ds_;
    float cacc[4] = {0.f, 0.f, 0.f, 0.f};
    for (int g = wave; g * 16 < c; g += 4) {
        int tb = g * 16;
        int rA = tb + l15; if (rA >= c) rA = c - 1;
        int mA = lst[rA];
        const f16* na = nb + (size_t)mA * 64;
        f16x8 a0 = *(const f16x8*)&na[quad * 8];
        f16x8 a1 = *(const f16x8*)&na[32 + quad * 8];
        if (sb) {
            // layer 0: acc1 = nrm@D, acc2 = nrm@G; out = relu(acc1 + s_row*acc2 + gb)
            f32x4 acc1[4], acc2[4];
#pragma unroll
            for (int nt = 0; nt < 4; ++nt) {
                f32x4 c1 = {0.f, 0.f, 0.f, 0.f}, c2 = {0.f, 0.f, 0.f, 0.f};
                c1 = MFMA16(a0, dbf[(0 * 4 + nt) * 64 + lane], c1);
                c1 = MFMA16(a1, dbf[(1 * 4 + nt) * 64 + lane], c1);
                c2 = MFMA16(a0, gbf[(0 * 4 + nt) * 64 + lane], c2);
                c2 = MFMA16(a1, gbf[(1 * 4 + nt) * 64 + lane], c2);
                acc1[nt] = c1; acc2[nt] = c2;
            }
#pragma unroll
            for (int i = 0; i < 4; ++i) {
                int rr = tb + quad * 4 + i;
                if (rr < c) {
                    int m = lst[rr];
                    float sm = sb[m];
#pragma unroll
                    for (int nt = 0; nt < 4; ++nt) {
                        float v = fmaxf(fmaf(sm, acc2[nt][i], acc1[nt][i]) + gbl[nt], 0.f);
                        hob[(size_t)m * 64 + nt * 16 + l15] = (f16)v;
                    }
                }
            }
        } else {
            // layer 1: out = relu(nrm@D + h@G + gb)
            const f16* ha = hb + (size_t)mA * 64;
            f16x8 h0 = *(const f16x8*)&ha[quad * 8];
            f16x8 h1 = *(const f16x8*)&ha[32 + quad * 8];
            f32x4 acc[4];
#pragma unroll
            for (int nt = 0; nt < 4; ++nt) {
                f32x4 cc = {0.f, 0.f, 0.f, 0.f};
                cc = MFMA16(a0, dbf[(0 * 4 + nt) * 64 + lane], cc);
                cc = MFMA16(a1, dbf[(1 * 4 + nt) * 64 + lane], cc);
                cc = MFMA16(h0, gbf[(0 * 4 + nt) * 64 + lane], cc);
                cc = MFMA16(h1, gbf[(1 * 4 + nt) * 64 + lane], cc);
                acc[nt] = cc;
            }
#pragma unroll
            for (int i = 0; i < 4; ++i) {
                int rr = tb + quad * 4 + i;
                if (rr < c) {
                    int m = lst[rr];
#pragma unroll
                    for (int nt = 0; nt < 4; ++nt) {
                        float v = fmaxf(acc[nt][i] + gbl[nt], 0.f);
                        hob[(size_t)m * 64 + nt * 16 + l15] = (f16)v;
                        cacc[nt] += v;
                    }
                }
            }
        }
    }
    if (ctx) {
#pragma unroll
        for (int nt = 0; nt < 4; ++nt) {
            float sv = cacc[nt];
            sv += __shfl_xor(sv, 16, 64);
            sv += __shfl_xor(sv, 32, 64);
            if (quad == 0) atomicAdd(&ctx[b * HID + nt * 16 + l15], sv);
        }
    }
}

// ---------------- head + fused GRU: state from ctx (redundant per block),
//                  lat = relu([h2|st]@W1^T+b1)@w2 + b2   (h2 in f16)
__global__ __launch_bounds__(256) void k_head(
    const f16* __restrict__ h2, const float* __restrict__ ctx_sum,
    const float* __restrict__ prev,
    const float* __restrict__ w_ih, const float* __restrict__ w_hh,
    const float* __restrict__ b_ih, const float* __restrict__ b_hh,
    const f16* __restrict__ hwf, const float* __restrict__ b1,
    const float* __restrict__ w2, const float* __restrict__ b2,
    float* __restrict__ lat, float* __restrict__ state_out)
{
    __shared__ f16 ws_[6144];
    __shared__ __align__(16) float st[STATE];
    __shared__ float cs[HID], ps[STATE], gis[96], ghs[96];
    int tid = threadIdx.x, wave = tid >> 6, lane = tid & 63;
    int l15 = lane & 15, quad = lane >> 4;
    int b = blockIdx.x >> 4;
    { const uint4* s = (const uint4*)hwf; uint4* d = (uint4*)ws_;
      for (int i = tid; i < 768; i += 256) d[i] = s[i]; }
    if (tid < HID) cs[tid] = ctx_sum[b * HID + tid] * (1.f / NN);
    if (tid >= HID && tid < HID + STATE) ps[tid - HID] = prev[b * STATE + tid - HID];
    __syncthreads();
    if (tid < 96) {
        float gi = b_ih[tid];
#pragma unroll 8
        for (int k = 0; k < HID; ++k) gi = fmaf(w_ih[tid * HID + k], cs[k], gi);
        float gh = b_hh[tid];
#pragma unroll
        for (int k = 0; k < STATE; ++k) gh = fmaf(w_hh[tid * STATE + k], ps[k], gh);
        gis[tid] = gi; ghs[tid] = gh;
    }
    __syncthreads();
    if (tid < STATE) {
        float r = sigm(gis[tid] + ghs[tid]);
        float z = sigm(gis[32 + tid] + ghs[32 + tid]);
        float nn = tanhf(gis[64 + tid] + r * ghs[64 + tid]);
        float v = (1.f - z) * nn + z * ps[tid];
        st[tid] = v;
        if ((blockIdx.x & 15) == 0) state_out[b * STATE + tid] = v;
    }
    __syncthreads();
    float b1c[4], w2c[4];
#pragma unroll
    for (int nt = 0; nt < 4; ++nt) { b1c[nt] = b1[nt * 16 + l15]; w2c[nt] = w2[nt * 16 + l15]; }
    float b2v = b2[0];
    int tb = blockIdx.x * 64 + wave * 16;
    int grow = tb + l15;
    const f16* ha = h2 + (size_t)grow * 64;
    f16x8 a0 = *(const f16x8*)&ha[quad * 8];
    f16x8 a1 = *(const f16x8*)&ha[32 + quad * 8];
    const float4* sp = (const float4*)st;
    f16x8 a2 = cvt8(sp[quad * 2], sp[quad * 2 + 1]);
    const f16x8* bf = (const f16x8*)ws_;
    f32x4 acc[4];
#pragma unroll
    for (int nt = 0; nt < 4; ++nt) {
        f32x4 cc = {0.f, 0.f, 0.f, 0.f};
        cc = MFMA16(a0, bf[(0 * 4 + nt) * 64 + lane], cc);
        cc = MFMA16(a1, bf[(1 * 4 + nt) * 64 + lane], cc);
        cc = MFMA16(a2, bf[(2 * 4 + nt) * 64 + lane], cc);
        acc[nt] = cc;
    }
#pragma unroll
    for (int i = 0; i < 4; ++i) {
        float s = 0.f;
#pragma unroll
        for (int nt = 0; nt < 4; ++nt) s = fmaf(fmaxf(acc[nt][i] + b1c[nt], 0.f), w2c[nt], s);
        s += __shfl_xor(s, 1, 64); s += __shfl_xor(s, 2, 64);
        s += __shfl_xor(s, 4, 64); s += __shfl_xor(s, 8, 64);
        if (l15 == 0) lat[tb + quad * 4 + i] = s + b2v;
    }
}

extern "C" void kernel_launch(void* const* d_in, const int* in_sizes, int n_in,
                              void* d_out, int out_size, void* d_ws, size_t ws_size,
                              hipStream_t stream) {
    const float* feat   = (const float*)d_in[0];
    const int*   types  = (const int*)d_in[1];
    const float* prev   = (const float*)d_in[2];
    const float* enc_w1 = (const float*)d_in[3];
    const float* enc_b1 = (const float*)d_in[4];
    const float* enc_w2 = (const float*)d_in[5];
    const float* enc_b2 = (const float*)d_in[6];
    const float* cont   = (const float*)d_in[7];
    const float* gnn_w  = (const float*)d_in[8];
    const float* gnn_b  = (const float*)d_in[9];
    const float* w_ih   = (const float*)d_in[10];
    const float* w_hh   = (const float*)d_in[11];
    const float* b_ih   = (const float*)d_in[12];
    const float* b_hh   = (const float*)d_in[13];
    const float* hw1    = (const float*)d_in[14];
    const float* hb1    = (const float*)d_in[15];
    const float* hw2    = (const float*)d_in[16];
    const float* hb2    = (const float*)d_in[17];
    float* out = (float*)d_out;

    float* ws  = (float*)d_ws;
    f16*   nrm = (f16*)ws;                    // 4194304 f16
    f16*   h1  = (f16*)(ws + 2097152);        // 4194304 f16
    f16*   h2  = (f16*)(ws + 4194304);        // 4194304 f16
    float* scl = ws + 6291456;                // 65536 f32
    int*   idx = (int*)(ws + 6356992);        // 655360 i32
    int*   cnt = idx + BB * NTYPES * NN;      // 640 i32
    f16*   M0  = (f16*)(ws + 7012992);        // 2621440 f16
    f16*   M1  = (f16*)(ws + 8323712);        // 2621440 f16
    f16*   wfrag = (f16*)(ws + 9634432);      // 18432 f16
    float* ctx   = ws + 9643648;              // 4096 f32
    f16*   w2f  = wfrag;
    f16*   gw0f = wfrag + 4096;
    f16*   gw1f = wfrag + 8192;
    f16*   hwf  = wfrag + 12288;

    k_misc<<<91, 256, 0, stream>>>(enc_w2, gnn_w, hw1, wfrag, cnt, ctx);
    k_encoder<<<BB * NN / 64, 256, 0, stream>>>(feat, enc_w1, enc_b1, w2f, enc_b2,
                                                types, idx, cnt, nrm, scl);
    // layer 0: h0 = scl*nrm -> h1
    k_buildM<<<BB * NTYPES, 256, 0, stream>>>(idx, cnt, nrm, nrm, scl, M0);
    k_gnn_layer<<<BB * NTYPES, 256, 0, stream>>>(idx, cnt, cont, M0, nrm, nrm, scl,
                                                 gw0f, gnn_b, h1, nullptr);
    // layer 1: h1 -> h2, fused ctx accumulation
    k_buildM<<<BB * NTYPES, 256, 0, stream>>>(idx, cnt, nrm, h1, nullptr, M1);
    k_gnn_layer<<<BB * NTYPES, 256, 0, stream>>>(idx, cnt, cont, M1, nrm, h1, nullptr,
                                                 gw1f, gnn_b + HID, h2, ctx);
    // head (+ fused GRU); new_state written to out tail
    k_head<<<BB * NN / 64, 256, 0, stream>>>(h2, ctx, prev, w_ih, w_hh, b_ih, b_hh,
                                             hwf, hb1, hw2, hb2, out, out + BB * NN);
}